// Round 20
// baseline (369.212 us; speedup 1.0000x reference)
//
#include <hip/hip_runtime.h>
#include <hip/hip_bf16.h>

#define EPSV 1e-5f

// workspace layout: [wB2][xTp][stats] — K-loop B-prefetch overshoots by up to
// 2 steps (8 KB) past a (p,nt) slab: lands in the next slab or (for the very
// last slab) in xTp — dead values, always inside ws. A-prefetch overshoot at
// u=36 stays inside Atile (max index 8856 < 30720). Both verified.
#define WB2_ELEMS (2*8*36*128*32)          // [p][nt(8)][kt(36)][nl(128)][kk(32)] bf16
#define WB2_BYTES ((size_t)WB2_ELEMS*2)    // 4,718,592
#define XTP_ELEMS (8*68*68*128)            // padded channels-last x, bf16
#define XTP_BYTES ((size_t)XTP_ELEMS*2)    // 9,469,952
#define STATS_OFF (WB2_BYTES + XTP_BYTES)  // 1024 float2 partials

typedef __attribute__((ext_vector_type(8))) short short8;
typedef __attribute__((ext_vector_type(4))) float f32x4;

// ---------------------------------------------------------------------------
// x [8][128][64][64] f32  ->  xTp [8][68][68][128] bf16 (2-px zero halo)
__global__ __launch_bounds__(256) void k_xpad(const float* __restrict__ x,
                                              __hip_bfloat16* __restrict__ xTp) {
    int bh = blockIdx.x; int b = bh >> 6, h = bh & 63;
    __shared__ __hip_bfloat16 tile[64][130];
    int t = threadIdx.x;
#pragma unroll
    for (int i = 0; i < 32; ++i) {
        int e = (i << 8) + t; int w = e & 63; int ci = e >> 6;
        tile[w][ci] = __float2bfloat16(x[(((size_t)(b*128 + ci))*64 + h)*64 + w]);
    }
    __syncthreads();
    __hip_bfloat16* dst = xTp + ((size_t)((b*68 + h + 2)*68 + 2))*128;
#pragma unroll
    for (int i = 0; i < 32; ++i) {
        int e = (i << 8) + t; int ci = e & 127; int w = e >> 7;
        dst[w*128 + ci] = tile[w][ci];
    }
}

// ---------------------------------------------------------------------------
// w_mid [128][16][128][3][3] f32 -> wB2 [p][nt(8)][kt(36)][nl(128)][kk(32)]
__global__ void k_wrepack(const float* __restrict__ w_mid,
                          __hip_bfloat16* __restrict__ wB2) {
    int idx = blockIdx.x * 256 + threadIdx.x;
    if (idx >= WB2_ELEMS) return;
    int kk  = idx & 31;
    int nl  = (idx >> 5) & 127;
    int q   = idx >> 12;             // (p*8+nt)*36 + kt
    int kt  = q % 36;
    int pnt = q / 36;
    int nt  = pnt & 7, p = pnt >> 3;
    int c = ((nt*8 + (nl >> 4)) << 1) + p;
    int m = nl & 15;
    int k = kt*32 + kk;
    int tap = k >> 7, ci = k & 127;
    wB2[idx] = __float2bfloat16(w_mid[((size_t)((c*16 + m)*128 + ci))*9 + tap]);
}

// ---------------------------------------------------------------------------
// Persistent-A implicit-GEMM conv, barrier-free K-loop — ROLLED CODE build.
// Identical schedule/memory structure to the previous (passing) round; the
// only change is code size: K-loop rolled to 6 outer x 6-step body (static
// &1/%3 slot indices), staging and epilogue-j rolled. Hot body ~2.5 KB vs
// ~20 KB unrolled — tests the I$-thrash hypothesis for the 246-us plateau.
__global__ __launch_bounds__(256, 2) void k_conv(
    const __hip_bfloat16* __restrict__ xTp,
    const __hip_bfloat16* __restrict__ wB2,
    const float* __restrict__ w_pt,
    const float* __restrict__ b_pt,
    float* __restrict__ y) {
    __shared__ __hip_bfloat16 Atile[4*240*32];   // 61,440 B; plane kc: ci kc*32..+32

    const int combo = blockIdx.x & 7;      // XCD
    const int p   = combo & 1;
    const int ntp = combo >> 1;            // nt-pair 0..3
    const int i_  = blockIdx.x >> 3;       // 0..511
    const int nt  = ntp*2 + (i_ >> 8);
    const int mt  = i_ & 255;              // 0..255
    const int dil = 1 + p;
    const int b  = mt >> 5;                // image
    const int hb = (mt >> 2) & 7;          // row-block: output rows hb*8..+8
    const int wb = mt & 3;                 // col-block: output cols wb*16..+16
    const int H0 = hb*8, W0 = wb*16;       // halo origin (padded coords)

    const int t = threadIdx.x, lane = t & 63, wave = t >> 6;
    const int wm = wave >> 1, wn = wave & 1;
    const int lm = lane & 15, lg = lane >> 4;

    // ---- stage halo once (rolled): 4 planes x 240 px x 4 slots = 3840 units
    // phys slot = ls ^ ((px>>1)&3)   (R6 mechanism, R10/R17 zero-conflict shape)
    {
        const size_t gbase = ((size_t)(b*68 + H0))*68 + W0;
#pragma unroll 1
        for (int pass = 0; pass < 15; ++pass) {
            int si  = pass*256 + t;          // 0..3839
            int kc  = si / 960;
            int rem = si - kc*960;
            int px  = rem >> 2;
            int ls  = rem & 3;
            int prow = px / 20, pcol = px - prow*20;
            short8 v = *(const short8*)(xTp + (gbase + prow*68 + pcol)*128
                                        + kc*32 + ls*8);
            int phys = ls ^ ((px >> 1) & 3);
            *(short8*)(Atile + (kc*960 + px*4 + phys)*8) = v;
        }
    }

    // B pointer: frag j at step u = +u*4096 + j*512
    const __hip_bfloat16* bptr = wB2 + (size_t)p*(8*36*4096) + (size_t)nt*(36*4096)
                               + (wn*64 + lm)*32 + lg*8;

    f32x4 acc[4][4];
#pragma unroll
    for (int i = 0; i < 4; ++i)
#pragma unroll
        for (int j = 0; j < 4; ++j) acc[i][j] = (f32x4){0.f, 0.f, 0.f, 0.f};

    // B prologue: steps 0,1 into breg[0],breg[1]
    short8 breg[3][4];
#pragma unroll
    for (int j = 0; j < 4; ++j) breg[0][j] = *(const short8*)(bptr + j*512);
#pragma unroll
    for (int j = 0; j < 4; ++j) breg[1][j] = *(const short8*)(bptr + 4096 + j*512);

    __syncthreads();   // staging visible; the ONLY block-wide barrier

    // A fragment read, runtime tap (same formula as the compile-time version)
#define LOADA_DYN(dst, khc, kwc, kcc) do {                                    \
    int pc_ = 2 + dil*(kwc) + lm;                                             \
    int pr_ = (wm*4 + 2 + dil*(khc))*20 + pc_;                                \
    _Pragma("unroll")                                                         \
    for (int i_a = 0; i_a < 4; ++i_a) {                                       \
        int px_ = pr_ + 20*i_a;                                               \
        dst[i_a] = *(const short8*)(Atile + (kcc)*7680 + px_*32               \
                                    + ((lg ^ ((px_ >> 1) & 3)) << 3));        \
    }                                                                         \
  } while (0)

    short8 af[2][4];
    LOADA_DYN(af[0], -1, -1, 0);   // fragments for step u=0 (tap 0, kc 0)

    const __hip_bfloat16* bpre = bptr + 8192;   // prefetch source for step u+2

#pragma unroll 1
    for (int v = 0; v < 6; ++v) {
#pragma unroll
        for (int s = 0; s < 6; ++s) {
            // u = 6*v + s; u&1 == s&1, u%3 == s%3 (6v ≡ 0 mod 2,3)
            // B prefetch for step u+2 into static slot (s+2)%3 (dead overshoot
            // reads for u+2 >= 36 — in-bounds of ws)
#pragma unroll
            for (int j = 0; j < 4; ++j)
                breg[(s+2)%3][j] = *(const short8*)(bpre + j*512);
            bpre += 4096;
            // A fragment prefetch for step u+1 into static slot (s+1)&1
            {
                int un = 6*v + s + 1;
                int tap = un >> 2, kc = un & 3;
                int q3 = (tap*11) >> 5;            // tap/3 for 0..9
                int kh = q3 - 1, kw = tap - 3*q3 - 1;
                LOADA_DYN(af[(s+1)&1], kh, kw, kc);
            }
            __builtin_amdgcn_sched_barrier(0);
#pragma unroll
            for (int i = 0; i < 4; ++i)
#pragma unroll
                for (int j = 0; j < 4; ++j)
                    acc[i][j] = __builtin_amdgcn_mfma_f32_16x16x32_bf16(
                        af[s&1][i], breg[s%3][j], acc[i][j], 0, 0, 0);
        }
    }
#undef LOADA_DYN

    // epilogue (j rolled): leaky -> *w_pt -> 16-lane reduce -> +b_pt -> y
#pragma unroll 1
    for (int j = 0; j < 4; ++j) {
        int n_g = nt*128 + wn*64 + j*16 + lm;
        int c = ((n_g >> 4) << 1) + p;     // uniform across the 16-lane group
        float wp = w_pt[c*16 + lm];        // m == lm
        float bp = b_pt[c];
#pragma unroll
        for (int i = 0; i < 4; ++i) {
            int h = H0 + wm*4 + i;
#pragma unroll
            for (int r = 0; r < 4; ++r) {
                float v = acc[i][j][r];
                v = v >= 0.f ? v : 0.1f*v;
                v *= wp;
                v += __shfl_xor(v, 1);
                v += __shfl_xor(v, 2);
                v += __shfl_xor(v, 4);
                v += __shfl_xor(v, 8);
                if (lm == 0) {
                    int w = W0 + lg*4 + r;
                    y[(size_t)(b*128 + c)*4096 + h*64 + w] = v + bp;
                }
            }
        }
    }
}

// ---------------------------------------------------------------------------
// per-(b,c)-plane partial sums (float4 loads, no atomics, deterministic)
__global__ __launch_bounds__(256) void k_ystat(const float* __restrict__ y,
                                               float2* __restrict__ partials) {
    int P = blockIdx.x;                 // plane = b*128 + c
    const float4* base = (const float4*)(y + (size_t)P*4096);
    int t = threadIdx.x;
    float s = 0.f, s2 = 0.f;
#pragma unroll
    for (int i = 0; i < 4; ++i) {
        float4 v = base[t + i*256];
        s  += v.x + v.y + v.z + v.w;
        s2 += v.x*v.x + v.y*v.y + v.z*v.z + v.w*v.w;
    }
#pragma unroll
    for (int o = 32; o; o >>= 1) { s += __shfl_down(s, o); s2 += __shfl_down(s2, o); }
    __shared__ float ss[4], ss2[4];
    if ((t & 63) == 0) { ss[t >> 6] = s; ss2[t >> 6] = s2; }
    __syncthreads();
    if (t == 0)
        partials[P] = make_float2(ss[0]+ss[1]+ss[2]+ss[3], ss2[0]+ss2[1]+ss2[2]+ss2[3]);
}

// BN finalize + apply + ReLU. Block covers 256 float4 = quarter of one plane.
__global__ __launch_bounds__(256) void k_bn_apply(float* __restrict__ y,
                                                  const float2* __restrict__ partials,
                                                  const float* __restrict__ gamma,
                                                  const float* __restrict__ beta) {
    int bid = blockIdx.x;
    int c = (bid >> 2) & 127;
    float s = 0.f, s2 = 0.f;
#pragma unroll
    for (int b = 0; b < 8; ++b) {
        float2 pr = partials[b*128 + c];
        s += pr.x; s2 += pr.y;
    }
    float mean = s * (1.f/32768.f);
    float var  = s2 * (1.f/32768.f) - mean*mean;
    float scale = gamma[c] * rsqrtf(var + EPSV);
    float shift = beta[c] - mean*scale;
    float4* y4 = (float4*)y;
    int idx = bid*256 + threadIdx.x;
    float4 v = y4[idx];
    v.x = fmaxf(v.x*scale + shift, 0.f);
    v.y = fmaxf(v.y*scale + shift, 0.f);
    v.z = fmaxf(v.z*scale + shift, 0.f);
    v.w = fmaxf(v.w*scale + shift, 0.f);
    y4[idx] = v;
}

// ---------------------------------------------------------------------------
extern "C" void kernel_launch(void* const* d_in, const int* in_sizes, int n_in,
                              void* d_out, int out_size, void* d_ws, size_t ws_size,
                              hipStream_t stream) {
    const float* x     = (const float*)d_in[0];
    const float* w_mid = (const float*)d_in[1];
    const float* w_pt  = (const float*)d_in[2];
    const float* b_pt  = (const float*)d_in[3];
    const float* gamma = (const float*)d_in[4];
    const float* beta  = (const float*)d_in[5];
    float* y = (float*)d_out;

    __hip_bfloat16* wB2 = (__hip_bfloat16*)d_ws;
    __hip_bfloat16* xTp = (__hip_bfloat16*)((char*)d_ws + WB2_BYTES);
    float2* partials    = (float2*)((char*)d_ws + STATS_OFF);

    hipMemsetAsync(xTp, 0, XTP_BYTES, stream);                  // zero halo
    k_xpad<<<512, 256, 0, stream>>>(x, xTp);
    k_wrepack<<<(WB2_ELEMS + 255) / 256, 256, 0, stream>>>(w_mid, wB2);
    k_conv<<<4096, 256, 0, stream>>>(xTp, wB2, w_pt, b_pt, y);
    k_ystat<<<1024, 256, 0, stream>>>(y, partials);
    k_bn_apply<<<4096, 256, 0, stream>>>(y, partials, gamma, beta);
}

// Round 21
// 252.986 us; speedup vs baseline: 1.4594x; 1.4594x over previous
//
#include <hip/hip_runtime.h>
#include <hip/hip_bf16.h>

#define EPSV 1e-5f

// workspace layout: [wB2][xTp][stats]
#define WB2_ELEMS (2*4*36*256*32)          // [p][nt(4)][kt(36)][nl(256)][kk(32)] bf16
#define WB2_BYTES ((size_t)WB2_ELEMS*2)    // 4,718,592
#define XTP_ELEMS (8*68*68*128)            // padded channels-last x, bf16
#define XTP_BYTES ((size_t)XTP_ELEMS*2)    // 9,469,952
#define STATS_OFF (WB2_BYTES + XTP_BYTES)  // 1024 float2 partials

// k_conv dynamic LDS: 4 dbuf x (A 16 KB + B 16 KB) = 128 KB
#define CONV_LDS_BYTES (131072)

typedef __attribute__((ext_vector_type(8))) short short8;
typedef __attribute__((ext_vector_type(4))) float f32x4;

__device__ __forceinline__ void gload_lds16(const void* g, void* l) {
    __builtin_amdgcn_global_load_lds(
        (const __attribute__((address_space(1))) void*)g,
        (__attribute__((address_space(3))) void*)l, 16, 0, 0);
}

// ---------------------------------------------------------------------------
// x [8][128][64][64] f32  ->  xTp [8][68][68][128] bf16 (2-px zero halo)
__global__ __launch_bounds__(256) void k_xpad(const float* __restrict__ x,
                                              __hip_bfloat16* __restrict__ xTp) {
    int bh = blockIdx.x; int b = bh >> 6, h = bh & 63;
    __shared__ __hip_bfloat16 tile[64][130];
    int t = threadIdx.x;
#pragma unroll
    for (int i = 0; i < 32; ++i) {
        int e = (i << 8) + t; int w = e & 63; int ci = e >> 6;
        tile[w][ci] = __float2bfloat16(x[(((size_t)(b*128 + ci))*64 + h)*64 + w]);
    }
    __syncthreads();
    __hip_bfloat16* dst = xTp + ((size_t)((b*68 + h + 2)*68 + 2))*128;
#pragma unroll
    for (int i = 0; i < 32; ++i) {
        int e = (i << 8) + t; int ci = e & 127; int w = e >> 7;
        dst[w*128 + ci] = tile[w][ci];
    }
}

// ---------------------------------------------------------------------------
// w_mid [128][16][128][3][3] f32 -> wB2 [p][nt(4)][kt(36)][nl(256)][kk(32)]
// (R15-verbatim, passed)
__global__ void k_wrepack(const float* __restrict__ w_mid,
                          __hip_bfloat16* __restrict__ wB2) {
    int idx = blockIdx.x * 256 + threadIdx.x;
    if (idx >= WB2_ELEMS) return;
    int kk  = idx & 31;
    int nl  = (idx >> 5) & 255;
    int q   = idx >> 13;             // (p*4+nt)*36 + kt
    int kt  = q % 36;
    int pnt = q / 36;                // 0..7
    int nt  = pnt & 3, p = pnt >> 2;
    int c = ((nt*16 + (nl >> 4)) << 1) + p;
    int m = nl & 15;
    int k = kt*32 + kk;
    int tap = k >> 7, ci = k & 127;
    wB2[idx] = __float2bfloat16(w_mid[((size_t)((c*16 + m)*128 + ci))*9 + tap]);
}

// ---------------------------------------------------------------------------
// Implicit-GEMM conv — m201 8-phase-template port. BM=256 x BN=256, BK=32,
// 36 K-tiles, 8 waves (2M x 4N), acc 8x4. 4 rotating LDS dbufs (128 KB):
// ktile kt in dbuf kt&3; its 2 phases stage ktile kt+2 into dbuf (kt+2)&3
// (last read 4 barriers earlier — WAR-safe). Counted vmcnt(4) ONLY at ktile
// boundaries (q=1); drains to 0 only at kt=34. Per phase: ds_read frags ->
// 2 gload_lds -> [vmcnt] -> s_barrier -> lgkmcnt(0) -> sched_barrier ->
// setprio(1) -> 16 MFMA -> setprio(0). All addressing R15-verbatim (passed).
__global__ __launch_bounds__(512, 2) void k_conv(
    const __hip_bfloat16* __restrict__ xTp,
    const __hip_bfloat16* __restrict__ wB2,
    const float* __restrict__ w_pt,
    const float* __restrict__ b_pt,
    float* __restrict__ y) {
    extern __shared__ char smem[];
    __hip_bfloat16* Ae = (__hip_bfloat16*)smem;              // 4 x 8192 elems
    __hip_bfloat16* Be = (__hip_bfloat16*)(smem + 65536);    // 4 x 8192 elems

    const int combo = blockIdx.x & 7;      // XCD: one (p, nt) each
    const int p  = combo & 1;
    const int nt = combo >> 1;             // 0..3
    const int mt = blockIdx.x >> 3;        // 0..127 (256 spatial rows each)
    const int dil = 1 + p;

    const int t = threadIdx.x;             // 0..511
    const int lane = t & 63;
    const int wave = t >> 6;               // 0..7
    const int wm = wave >> 2;              // 0..1
    const int wn = wave & 3;               // 0..3
    const int lm = lane & 15, lg = lane >> 4;

    // ---- staging addressing (R15-verbatim) ----
    const int rsub = t >> 2;                              // row 0..127
    const int ksub = (((t & 3) ^ ((t >> 3) & 3)) << 3);   // src-side swizzled slot
    const __hip_bfloat16* abase0;
    const __hip_bfloat16* abase1;
    {
        int s0 = mt*256 + rsub;
        int s1 = s0 + 128;
        abase0 = xTp + ((size_t)(((s0>>12)*68 + ((s0>>6)&63) + 2)*68 + (s0&63) + 2))*128 + ksub;
        abase1 = xTp + ((size_t)(((s1>>12)*68 + ((s1>>6)&63) + 2)*68 + (s1&63) + 2))*128 + ksub;
    }
    const __hip_bfloat16* bbase = wB2 + (size_t)(p*4 + nt)*(36*8192)
                                + rsub*32 + ksub;

    // ---- ds-read offsets (R15-verbatim swizzle) ----
    const int sslot = (lg ^ ((lm >> 1) & 3)) << 3;
    const int aoffb = (wm*128 + lm)*32 + sslot;     // + i*512 + dbuf*8192
    const int boffb = (wn*64 + lm)*32 + sslot;      // + j*512 + dbuf*8192

    f32x4 acc[8][4];
#pragma unroll
    for (int i = 0; i < 8; ++i)
#pragma unroll
        for (int j = 0; j < 4; ++j) acc[i][j] = (f32x4){0.f, 0.f, 0.f, 0.f};

    // ---- prologue: stage kt0 -> dbuf0, kt1 -> dbuf1 (8 loads), vmcnt(4) ----
    {
        const int t0 = -dil*8832;    // tap 0: kh=-1, kw=-1; ci0 = 0
        gload_lds16(abase0 + t0,      smem           + (0*512 + t)*16);
        gload_lds16(abase1 + t0,      smem           + (1*512 + t)*16);
        gload_lds16(bbase,            smem + 65536   + (0*512 + t)*16);
        gload_lds16(bbase + 4096,     smem + 65536   + (1*512 + t)*16);
        gload_lds16(abase0 + t0 + 32, smem + 16384   + (0*512 + t)*16);
        gload_lds16(abase1 + t0 + 32, smem + 16384   + (1*512 + t)*16);
        gload_lds16(bbase + 8192,     smem + 81920   + (0*512 + t)*16);
        gload_lds16(bbase + 12288,    smem + 81920   + (1*512 + t)*16);
    }
    asm volatile("s_waitcnt vmcnt(4)" ::: "memory");   // kt0 resident, kt1 in flight
    __builtin_amdgcn_s_barrier();
    __builtin_amdgcn_sched_barrier(0);

    // ---- K-loop: kt = 4*vv + ss, 2 phases (q) per ktile ----
#pragma unroll 1
    for (int vv = 0; vv < 9; ++vv) {
        // tap pixel offsets for staging ktile kt+2 (taps vv and vv+1)
        const int q3c = (vv*11) >> 5;
        const int toff_c = dil*128*((q3c - 1)*68 + (vv - 3*q3c - 1));
        const int vn = vv + 1;
        const int q3n = (vn*11) >> 5;
        const int toff_n = dil*128*((q3n - 1)*68 + (vn - 3*q3n - 1));
#pragma unroll
        for (int ss = 0; ss < 4; ++ss) {
            const int d  = ss;                 // dbuf of ktile kt (static)
            const int d2 = (ss + 2) & 3;       // dbuf staged (static)
            const bool do_stage = (vv < 8) || (ss < 2);   // kt+2 < 36
            short8 bf[4];
            short8 af[4];
#pragma unroll
            for (int q = 0; q < 2; ++q) {
                // ds_read this phase's fragments (data guaranteed by prior boundary)
                if (q == 0) {
#pragma unroll
                    for (int j = 0; j < 4; ++j)
                        bf[j] = *(const short8*)(Be + d*8192 + boffb + j*512);
                }
#pragma unroll
                for (int ii = 0; ii < 4; ++ii)
                    af[ii] = *(const short8*)(Ae + d*8192 + aoffb + (q*4 + ii)*512);
                // stage half of ktile kt+2 (q0: A, q1: B)
                if (do_stage) {
                    if (q == 0) {
                        const int aoff = (ss < 2) ? (toff_c + (ss + 2)*32)
                                                  : (toff_n + (ss - 2)*32);
                        gload_lds16(abase0 + aoff, smem + d2*16384 + (0*512 + t)*16);
                        gload_lds16(abase1 + aoff, smem + d2*16384 + (1*512 + t)*16);
                    } else {
                        const size_t bo = (size_t)(4*vv + ss + 2)*8192;
                        gload_lds16(bbase + bo,        smem + 65536 + d2*16384 + (0*512 + t)*16);
                        gload_lds16(bbase + bo + 4096, smem + 65536 + d2*16384 + (1*512 + t)*16);
                    }
                }
                // ktile boundary: guarantee ktile kt+1 resident; never drain
                // below 4 except the kt=34 tail
                if (q == 1) {
                    if (ss == 2) {
                        if (vv == 8) asm volatile("s_waitcnt vmcnt(0)" ::: "memory");
                        else         asm volatile("s_waitcnt vmcnt(4)" ::: "memory");
                    } else {
                        asm volatile("s_waitcnt vmcnt(4)" ::: "memory");
                    }
                }
                __builtin_amdgcn_s_barrier();
                asm volatile("s_waitcnt lgkmcnt(0)" ::: "memory");
                __builtin_amdgcn_sched_barrier(0);
                __builtin_amdgcn_s_setprio(1);
#pragma unroll
                for (int ii = 0; ii < 4; ++ii)
#pragma unroll
                    for (int j = 0; j < 4; ++j)
                        acc[q*4 + ii][j] = __builtin_amdgcn_mfma_f32_16x16x32_bf16(
                            af[ii], bf[j], acc[q*4 + ii][j], 0, 0, 0);
                __builtin_amdgcn_s_setprio(0);
            }
        }
    }

    // ---- epilogue (R15-verbatim): leaky -> *w_pt -> 16-lane reduce -> +b_pt ----
#pragma unroll
    for (int j = 0; j < 4; ++j) {
        int n_g = nt*256 + wn*64 + j*16 + lm;
        int c = ((n_g >> 4) << 1) + p;     // uniform across the 16-lane group
        float wp = w_pt[c*16 + lm];        // m == lm
        float bp = b_pt[c];
#pragma unroll
        for (int i = 0; i < 8; ++i) {
#pragma unroll
            for (int r = 0; r < 4; ++r) {
                float v = acc[i][j][r];
                v = v >= 0.f ? v : 0.1f*v;
                v *= wp;
                v += __shfl_xor(v, 1);
                v += __shfl_xor(v, 2);
                v += __shfl_xor(v, 4);
                v += __shfl_xor(v, 8);
                if (lm == 0) {
                    int s = mt*256 + wm*128 + i*16 + lg*4 + r;
                    int b = s >> 12, hw = s & 4095;
                    y[(size_t)(b*128 + c)*4096 + hw] = v + bp;
                }
            }
        }
    }
}

// ---------------------------------------------------------------------------
// per-(b,c)-plane partial sums (float4 loads, no atomics, deterministic)
__global__ __launch_bounds__(256) void k_ystat(const float* __restrict__ y,
                                               float2* __restrict__ partials) {
    int P = blockIdx.x;                 // plane = b*128 + c
    const float4* base = (const float4*)(y + (size_t)P*4096);
    int t = threadIdx.x;
    float s = 0.f, s2 = 0.f;
#pragma unroll
    for (int i = 0; i < 4; ++i) {
        float4 v = base[t + i*256];
        s  += v.x + v.y + v.z + v.w;
        s2 += v.x*v.x + v.y*v.y + v.z*v.z + v.w*v.w;
    }
#pragma unroll
    for (int o = 32; o; o >>= 1) { s += __shfl_down(s, o); s2 += __shfl_down(s2, o); }
    __shared__ float ss[4], ss2[4];
    if ((t & 63) == 0) { ss[t >> 6] = s; ss2[t >> 6] = s2; }
    __syncthreads();
    if (t == 0)
        partials[P] = make_float2(ss[0]+ss[1]+ss[2]+ss[3], ss2[0]+ss2[1]+ss2[2]+ss2[3]);
}

// BN finalize + apply + ReLU. Block covers 256 float4 = quarter of one plane.
__global__ __launch_bounds__(256) void k_bn_apply(float* __restrict__ y,
                                                  const float2* __restrict__ partials,
                                                  const float* __restrict__ gamma,
                                                  const float* __restrict__ beta) {
    int bid = blockIdx.x;
    int c = (bid >> 2) & 127;
    float s = 0.f, s2 = 0.f;
#pragma unroll
    for (int b = 0; b < 8; ++b) {
        float2 pr = partials[b*128 + c];
        s += pr.x; s2 += pr.y;
    }
    float mean = s * (1.f/32768.f);
    float var  = s2 * (1.f/32768.f) - mean*mean;
    float scale = gamma[c] * rsqrtf(var + EPSV);
    float shift = beta[c] - mean*scale;
    float4* y4 = (float4*)y;
    int idx = bid*256 + threadIdx.x;
    float4 v = y4[idx];
    v.x = fmaxf(v.x*scale + shift, 0.f);
    v.y = fmaxf(v.y*scale + shift, 0.f);
    v.z = fmaxf(v.z*scale + shift, 0.f);
    v.w = fmaxf(v.w*scale + shift, 0.f);
    y4[idx] = v;
}

// ---------------------------------------------------------------------------
extern "C" void kernel_launch(void* const* d_in, const int* in_sizes, int n_in,
                              void* d_out, int out_size, void* d_ws, size_t ws_size,
                              hipStream_t stream) {
    const float* x     = (const float*)d_in[0];
    const float* w_mid = (const float*)d_in[1];
    const float* w_pt  = (const float*)d_in[2];
    const float* b_pt  = (const float*)d_in[3];
    const float* gamma = (const float*)d_in[4];
    const float* beta  = (const float*)d_in[5];
    float* y = (float*)d_out;

    __hip_bfloat16* wB2 = (__hip_bfloat16*)d_ws;
    __hip_bfloat16* xTp = (__hip_bfloat16*)((char*)d_ws + WB2_BYTES);
    float2* partials    = (float2*)((char*)d_ws + STATS_OFF);

    // opt in to >64 KB dynamic LDS for k_conv (host-side, graph-capture-safe)
    (void)hipFuncSetAttribute((const void*)k_conv,
                              hipFuncAttributeMaxDynamicSharedMemorySize,
                              CONV_LDS_BYTES);

    hipMemsetAsync(xTp, 0, XTP_BYTES, stream);                  // zero halo
    k_xpad<<<512, 256, 0, stream>>>(x, xTp);
    k_wrepack<<<(WB2_ELEMS + 255) / 256, 256, 0, stream>>>(w_mid, wB2);
    k_conv<<<1024, 512, CONV_LDS_BYTES, stream>>>(xTp, wB2, w_pt, b_pt, y);
    k_ystat<<<1024, 256, 0, stream>>>(y, partials);
    k_bn_apply<<<4096, 256, 0, stream>>>(y, partials, gamma, beta);
}